// Round 7
// baseline (20.545 us; speedup 1.0000x reference)
//
#include <hip/hip_runtime.h>
#include <math.h>

constexpr int Bn = 1024, Tn = 6, Vn = 100, Pn = 20, Cn = 3;
constexpr int PARTS = 4;
constexpr int F4PP = 250;              // float4s per part (1000/4)
constexpr int LPP = Vn / PARTS;        // 25 lanes per part
constexpr int NT1 = 128;
constexpr int NT2 = 128;
constexpr unsigned TAG = 0x13579BDFu;

__device__ __forceinline__ float sqd(float px, float py, float x, float y) {
    float dx = px - x, dy = py - y;
    return fmaf(dx, dx, dy * dy);
}

__device__ __forceinline__ void coords(float4 q, bool nb,
                                       float& x0, float& y0,
                                       float& x1, float& y1) {
    x0 = nb ? 1e6f : fmaf(q.x, 30.f, -15.f);
    y0 = nb ? 1e6f : fmaf(q.y, 60.f, -30.f);
    x1 = nb ? 1e6f : fmaf(q.z, 30.f, -15.f);
    y1 = nb ? 1e6f : fmaf(q.w, 60.f, -30.f);
}

// k1: one block per (b, quarter). Writes packed (val,idx) per t.
__global__ __launch_bounds__(NT1) void pmbl_part(
    const float* __restrict__ ego,
    const float* __restrict__ lane,
    const float* __restrict__ score,
    unsigned long long* __restrict__ partial)   // (B, PARTS, Tn)
{
    const int bid = blockIdx.x;
    const int b = bid >> 2, part = bid & 3;
    const int tid = threadIdx.x;

    __shared__ int smL[LPP];
    __shared__ unsigned long long red[2][Tn];

    // all loads up front
    const float4* lp4 = reinterpret_cast<const float4*>(
        lane + (size_t)b * (Vn * Pn * 2));
    const int fbase = part * F4PP;
    float4 q0 = lp4[fbase + tid];
    const bool has1 = tid < F4PP - NT1;         // tid < 122
    float4 q1 = has1 ? lp4[fbase + tid + NT1] : make_float4(0.f,0.f,0.f,0.f);

    float scv = 0.f;
    if (tid < LPP)
        scv = score[(size_t)b * (Vn * Cn) + (part * LPP + tid) * Cn + 2];

    float px[Tn], py[Tn];
    {
        const float* e = ego + (size_t)b * (Tn * 2);
        float cx = 0.f, cy = 0.f;
        #pragma unroll
        for (int t = 0; t < Tn; ++t) {
            cx += e[2 * t];
            cy += e[2 * t + 1];
            px[t] = cx; py[t] = cy;
        }
    }

    if (tid < LPP) smL[tid] = (scv < 0.5f) ? 1 : 0;
    __syncthreads();

    float best[Tn]; int bidx[Tn];
    #pragma unroll
    for (int t = 0; t < Tn; ++t) { best[t] = __builtin_inff(); bidx[t] = 0; }

    auto process = [&](int fl, float4 q) {     // fl = local float4 idx in part
        const int v = fl / 10;
        const bool nb = smL[v] != 0;
        float x0, y0, x1, y1;
        coords(q, nb, x0, y0, x1, y1);
        const int p0 = 2 * (fbase + fl), p1 = p0 + 1;   // GLOBAL point idx
        #pragma unroll
        for (int t = 0; t < Tn; ++t) {
            float s0 = sqd(px[t], py[t], x0, y0);
            float s1 = sqd(px[t], py[t], x1, y1);
            if (s0 < best[t]) { best[t] = s0; bidx[t] = p0; }
            if (s1 < best[t]) { best[t] = s1; bidx[t] = p1; }
        }
    };

    process(tid, q0);
    if (has1) process(tid + NT1, q1);

    unsigned long long pk[Tn];
    #pragma unroll
    for (int t = 0; t < Tn; ++t)
        pk[t] = (((unsigned long long)__float_as_uint(best[t])) << 32)
                | (unsigned)bidx[t];

    #pragma unroll
    for (int off = 32; off > 0; off >>= 1) {
        #pragma unroll
        for (int t = 0; t < Tn; ++t) {
            unsigned long long o = __shfl_xor(pk[t], off);
            pk[t] = (o < pk[t]) ? o : pk[t];
        }
    }
    if ((tid & 63) == 0) {
        #pragma unroll
        for (int t = 0; t < Tn; ++t) red[tid >> 6][t] = pk[t];
    }
    __syncthreads();

    if (tid < Tn) {
        unsigned long long a = red[0][tid], c = red[1][tid];
        partial[((size_t)b * PARTS + part) * Tn + tid] = (c < a) ? c : a;
    }
}

// k2: combine partials, intersections, tail, publish; block 0 gathers.
__global__ __launch_bounds__(NT2) void pmbl_tail(
    const float* __restrict__ ego,
    const float* __restrict__ lane,
    const float* __restrict__ score,
    float* __restrict__ out,
    const unsigned long long* __restrict__ partial,
    unsigned long long* __restrict__ slots)
{
    const int b = blockIdx.x;
    const int tid = threadIdx.x;

    __shared__ unsigned long long comb6[Tn];
    __shared__ int interMask;
    __shared__ double sm[NT2 / 64];

    if (tid == 0) interMask = 0;
    if (tid < Tn) {
        const unsigned long long* p = partial + (size_t)b * PARTS * Tn;
        unsigned long long m = p[tid];
        #pragma unroll
        for (int q = 1; q < PARTS; ++q) {
            unsigned long long c = p[q * Tn + tid];
            m = (c < m) ? c : m;
        }
        comb6[tid] = m;
    }

    float px[Tn], py[Tn], sx[Tn], sy[Tn];
    {
        const float* e = ego + (size_t)b * (Tn * 2);
        float cx = 0.f, cy = 0.f;
        #pragma unroll
        for (int t = 0; t < Tn; ++t) {
            sx[t] = cx; sy[t] = cy;
            cx += e[2 * t];
            cy += e[2 * t + 1];
            px[t] = cx; py[t] = cy;
        }
    }
    __syncthreads();

    // phase 2: 6*19 = 114 segment-intersection tests
    if (tid < Tn * (Pn - 1)) {
        const int t = tid / (Pn - 1);
        const int s = tid % (Pn - 1);
        unsigned idx = (unsigned)(comb6[t] & 0xffffffffu);
        unsigned vtu = idx / (unsigned)Pn;
        const int vt = (vtu < (unsigned)Vn) ? (int)vtu : 0;
        const bool nb = score[(size_t)b * (Vn * Cn) + vt * Cn + 2] < 0.5f;
        const float* lp = lane + ((size_t)b * Vn + vt) * (Pn * 2);
        float ax = nb ? 1e6f : fmaf(lp[2 * s + 0], 30.f, -15.f);
        float ay = nb ? 1e6f : fmaf(lp[2 * s + 1], 60.f, -30.f);
        float bx = nb ? 1e6f : fmaf(lp[2 * s + 2], 30.f, -15.f);
        float by = nb ? 1e6f : fmaf(lp[2 * s + 3], 60.f, -30.f);
        float d1x = px[t] - sx[t], d1y = py[t] - sy[t];
        float d2x = bx - ax, d2y = by - ay;
        float det = d1x * d2y - d1y * d2x;
        if (det != 0.f) {
            float dx = ax - sx[t], dy = ay - sy[t];
            float tt = (dx * d2y - dy * d2x) / det;
            float uu = (dx * d1y - dy * d1x) / det;
            if (tt >= 0.f && tt <= 1.f && uu >= 0.f && uu <= 1.f)
                atomicOr(&interMask, 1 << t);
        }
    }
    __syncthreads();

    if (tid == 0) {
        const int im = interMask;
        int first_t = Tn;
        #pragma unroll
        for (int t = Tn - 1; t >= 0; --t)
            if ((im >> t) & 1) first_t = t;
        float sum = 0.f;
        for (int t = 0; t < first_t; ++t) {
            float d = sqrtf(__uint_as_float((unsigned)(comb6[t] >> 32)));
            sum += (d > 1.f) ? 0.f : (1.f - d);
        }
        unsigned long long v = (((unsigned long long)TAG) << 32)
                             | (unsigned long long)__float_as_uint(sum);
        __hip_atomic_store(&slots[b], v, __ATOMIC_RELAXED,
                           __HIP_MEMORY_SCOPE_AGENT);
    }

    if (b == 0) {
        double s = 0.0;
        for (int j = tid; j < Bn; j += NT2) {
            unsigned long long v = __hip_atomic_load(
                &slots[j], __ATOMIC_RELAXED, __HIP_MEMORY_SCOPE_AGENT);
            while ((unsigned)(v >> 32) != TAG) {
                __builtin_amdgcn_s_sleep(2);
                v = __hip_atomic_load(&slots[j], __ATOMIC_RELAXED,
                                      __HIP_MEMORY_SCOPE_AGENT);
            }
            s += (double)__uint_as_float((unsigned)(v & 0xffffffffu));
        }
        #pragma unroll
        for (int off = 32; off > 0; off >>= 1) s += __shfl_xor(s, off);
        if ((tid & 63) == 0) sm[tid >> 6] = s;
        __syncthreads();
        if (tid == 0) {
            double tot = 0.0;
            #pragma unroll
            for (int w = 0; w < NT2 / 64; ++w) tot += sm[w];
            out[0] = (float)(tot / (double)(Bn * Tn));
        }
    }
}

extern "C" void kernel_launch(void* const* d_in, const int* in_sizes, int n_in,
                              void* d_out, int out_size, void* d_ws, size_t ws_size,
                              hipStream_t stream) {
    const float* ego   = (const float*)d_in[0];
    const float* lane  = (const float*)d_in[1];
    const float* score = (const float*)d_in[2];
    float* out = (float*)d_out;
    unsigned long long* partial = (unsigned long long*)d_ws;
    unsigned long long* slots   = partial + (size_t)Bn * PARTS * Tn;

    pmbl_part<<<Bn * PARTS, NT1, 0, stream>>>(ego, lane, score, partial);
    pmbl_tail<<<Bn, NT2, 0, stream>>>(ego, lane, score, out, partial, slots);
}